// Round 19
// baseline (626.656 us; speedup 1.0000x reference)
//
#include <hip/hip_runtime.h>
#include <cfloat>
#include <cmath>

#define NROWS 32768
#define DDIM  512
#define KCODES 2048

// output layout (floats): [loss][q_st N*512][perplexity][encodings N*K]
#define OUT_Q    1
#define OUT_PERP 16777217
#define OUT_ENC  16777218

// scratch offsets in float slots, relative to S = d_out + OUT_ENC + 2
#define AP_OFF    16777216    // 16,777,216  h split bf16 [32768][1024] (hi|lo)
#define BP_OFF    33554432    //  1,048,576  emb split bf16 [2048][1024]
#define XS_OFF    34603008    // 16,777,216  X split bf16 [32768][1024]
#define WS_OFF    51380224    //    262,144  W split bf16 [512][1024]
#define ENORM_OFF 51642368    //      2,048
#define PVAL_OFF  51644416    //    524,288 (16 x 32768)
#define PSEC_OFF  52692992    //    524,288
#define PIDX_OFF  53741568    //    524,288
#define PVAL2_OFF 63178752    //    262,144 (16 x 16384)
#define PSEC2_OFF 63703040    //    262,144
#define PIDX2_OFF 64227328    //    262,144
#define RB_OFF    64751616    //     32,768 (CAP2 x 8 chunk-best vals)
#define RI_OFF    64784384    //     32,768 (CAP2 x 8 chunk-best idx) -> end 64,817,152

#define CAP1 16384
#define CAP2 4096
#define EPS1 0.32f            // 1-term flag margin (r12-proven pass)
#define EPS2 0.02f            // 3-term flag margin (r3/r4-proven)

typedef __attribute__((ext_vector_type(8))) short  bf16x8;
typedef __attribute__((ext_vector_type(4))) float  f32x4;

__device__ __forceinline__ unsigned short f2bf(float f) {
  unsigned u = __float_as_uint(f);
  unsigned r = (u + 0x7FFF + ((u >> 16) & 1)) >> 16;
  return (unsigned short)r;
}
__device__ __forceinline__ float bf2f(unsigned short h) {
  return __uint_as_float(((unsigned)h) << 16);
}
__device__ __forceinline__ void gload16(const void* g, void* l) {
  __builtin_amdgcn_global_load_lds(
      (const __attribute__((address_space(1))) unsigned int*)g,
      (__attribute__((address_space(3))) unsigned int*)l, 16, 0, 0);
}
__device__ __forceinline__ ushort4 hi4(float4 v) {
  return make_ushort4(f2bf(v.x), f2bf(v.y), f2bf(v.z), f2bf(v.w));
}
__device__ __forceinline__ ushort4 lo4(float4 v, ushort4 h) {
  return make_ushort4(f2bf(v.x - bf2f(h.x)), f2bf(v.y - bf2f(h.y)),
                      f2bf(v.z - bf2f(h.z)), f2bf(v.w - bf2f(h.w)));
}

// ---- BK=64 single-buffer K-loop, 128x256 tile (32 MFMA per barrier) -----
// A rows addressed via per-thread offsets arow[4] (flags[]-indirect OK).
// B tile 256 rows; wave = 64M x 128N, acc[4][8].
template<int TERMS, int KSTEPS>
__device__ __forceinline__ void kloop64(const unsigned short* __restrict__ Abase,
    const unsigned short* __restrict__ Bm, const size_t* __restrict__ arow,
    short* Asm, short* Bsm, f32x4 (&acc)[4][8],
    int t, int wr, int wc, int lr, int lg) {
  for (int kt = 0; kt < KSTEPS; ++kt) {
    const int ph = kt >> 3, r64 = (kt & 7) * 64;
    int koffA, koffB;
    if (TERMS == 1)      { koffA = r64;                          koffB = r64; }
    else if (TERMS == 3) { koffA = (ph == 1) ? 512 + r64 : r64;  koffB = (ph == 2) ? 512 + r64 : r64; }
    else                 { koffA = (ph & 1) ? 512 + r64 : r64;   koffB = (ph & 2) ? 512 + r64 : r64; }
    const unsigned short* Bgp = Bm + koffB;
#pragma unroll
    for (int i = 0; i < 4; ++i) {
      const int chunk = i * 256 + t;
      const int r = chunk >> 3;
      const int c8s = (chunk & 7) ^ (r & 7);
      gload16(Abase + arow[i] + koffA + c8s * 8, Asm + chunk * 8);
    }
#pragma unroll
    for (int i = 0; i < 8; ++i) {
      const int chunk = i * 256 + t;
      const int r = chunk >> 3;
      const int c8s = (chunk & 7) ^ (r & 7);
      gload16(Bgp + (size_t)r * 1024 + c8s * 8, Bsm + chunk * 8);
    }
    __syncthreads();
#pragma unroll
    for (int kk = 0; kk < 2; ++kk) {
      const int xk = (kk * 32 + lg * 8) ^ ((lr & 7) << 3);
      bf16x8 a[4], b[8];
#pragma unroll
      for (int mi = 0; mi < 4; ++mi)
        a[mi] = *(const bf16x8*)&Asm[(wr * 64 + mi * 16 + lr) * 64 + xk];
#pragma unroll
      for (int ni = 0; ni < 8; ++ni)
        b[ni] = *(const bf16x8*)&Bsm[(wc * 128 + ni * 16 + lr) * 64 + xk];
#pragma unroll
      for (int mi = 0; mi < 4; ++mi)
#pragma unroll
        for (int ni = 0; ni < 8; ++ni)
          acc[mi][ni] = __builtin_amdgcn_mfma_f32_16x16x32_bf16(a[mi], b[ni], acc[mi][ni], 0, 0, 0);
    }
    __syncthreads();
  }
}

// ---- fully fused preprocessing -------------------------------------------
__global__ __launch_bounds__(256) void kprep(const float* __restrict__ x0,
    const float* __restrict__ x1, const float* __restrict__ W,
    const float* __restrict__ emb, unsigned short* __restrict__ Xs,
    unsigned short* __restrict__ Ws, unsigned short* __restrict__ Bp,
    float* __restrict__ enorms, unsigned int* __restrict__ wsclr) {
  const int bid = blockIdx.x;
  const int t = threadIdx.x;
  if (bid < 16384) {                     // x halves -> Xs
    const int i = bid * 256 + t;
    const int half = i >> 21;
    const int j = i & 2097151;
    const int n = j >> 6;
    const int c4 = (j & 63) * 4;
    const float* src = half ? x1 : x0;
    const float4 v = *(const float4*)&src[(size_t)n * 256 + c4];
    const ushort4 hh = hi4(v);
    unsigned short* row = Xs + (size_t)n * 1024 + half * 256;
    *(ushort4*)&row[c4]       = hh;
    *(ushort4*)&row[512 + c4] = lo4(v, hh);
  } else if (bid < 16640) {              // W -> Ws
    const int j = (bid - 16384) * 256 + t;
    const int r = j >> 7;
    const int c4 = (j & 127) * 4;
    const float4 v = *(const float4*)&W[(size_t)r * 512 + c4];
    const ushort4 hh = hi4(v);
    unsigned short* row = Ws + (size_t)r * 1024;
    *(ushort4*)&row[c4]       = hh;
    *(ushort4*)&row[512 + c4] = lo4(v, hh);
  } else if (bid == 16640) {             // ws header clear
    for (int i = t; i < 2052; i += 256) wsclr[i] = 0u;
  } else {                               // emb -> Bp + enorms (2 rows/block)
    __shared__ float part[4];
    const int row = (bid - 16641) * 2 + (t >> 7);
    const int c4 = (t & 127) * 4;
    const float4 v = *(const float4*)&emb[(size_t)row * 512 + c4];
    const ushort4 hh = hi4(v);
    unsigned short* brow = Bp + (size_t)row * 1024;
    *(ushort4*)&brow[c4]       = hh;
    *(ushort4*)&brow[512 + c4] = lo4(v, hh);
    float s = v.x * v.x + v.y * v.y + v.z * v.z + v.w * v.w;
#pragma unroll
    for (int off = 32; off > 0; off >>= 1) s += __shfl_down(s, off);
    if ((t & 63) == 0) part[t >> 6] = s;
    __syncthreads();
    if (t == 0)   enorms[row] = part[0] + part[1];
    if (t == 128) enorms[row] = part[2] + part[3];
  }
}

// ---- h = X @ W^T + b, 4-term split-bf16 MFMA; writes only Ap (hi|lo) ----
// 512 blocks: n = bid&1 (256-col panel), m = swizzled bid>>1.
__global__ __launch_bounds__(256) void kgemm1_mfma(
    const unsigned short* __restrict__ Xs, const unsigned short* __restrict__ Ws,
    const float* __restrict__ bias, unsigned short* __restrict__ Ap) {
  __shared__ short Asm[128 * 64];
  __shared__ short Bsm[256 * 64];
  const int bid = blockIdx.x;
  const int n = bid & 1;
  const int q = bid >> 1;
  const int m = (q & 7) * 32 + (q >> 3);
  const int m0 = m * 128, j0 = n * 256;
  const int t = threadIdx.x;
  const int wid = t >> 6, wr = wid >> 1, wc = wid & 1;
  const int lr = t & 15, lg = (t >> 4) & 3;
  size_t arow[4];
#pragma unroll
  for (int i = 0; i < 4; ++i)
    arow[i] = (size_t)(m0 + i * 32 + (t >> 3)) * 1024;

  f32x4 acc[4][8];
#pragma unroll
  for (int mi = 0; mi < 4; ++mi)
#pragma unroll
    for (int ni = 0; ni < 8; ++ni) acc[mi][ni] = (f32x4){0.f, 0.f, 0.f, 0.f};

  kloop64<4, 32>(Xs, Ws + (size_t)j0 * 1024, arow, Asm, Bsm, acc, t, wr, wc, lr, lg);

#pragma unroll
  for (int ni = 0; ni < 8; ++ni) {
    const int col = j0 + wc * 128 + ni * 16 + lr;
    const float bb = bias[col];
#pragma unroll
    for (int mi = 0; mi < 4; ++mi)
#pragma unroll
      for (int jj = 0; jj < 4; ++jj) {
        const int row = m0 + wr * 64 + mi * 16 + lg * 4 + jj;
        const float v = acc[mi][ni][jj] + bb;
        const unsigned short hb = f2bf(v);
        Ap[(size_t)row * 1024 + col]       = hb;
        Ap[(size_t)row * 1024 + 512 + col] = f2bf(v - bf2f(hb));
      }
  }
}

// ---- distance GEMM (argmin partials), 128x256 tile -----------------------
// partials: p = n*2 + wc (8 n-panels x 2 wave-cols = 16 of 128 codes each)
template<int TERMS, bool GATED>
__global__ __launch_bounds__(256) void kdist_t(
    const unsigned short* __restrict__ A, const unsigned short* __restrict__ B,
    const float* __restrict__ enorms, float* __restrict__ pval,
    float* __restrict__ psec, int* __restrict__ pidx,
    const int* __restrict__ nflag, const int* __restrict__ flags, int mrows) {
  __shared__ short Asm[128 * 64];
  __shared__ short Bsm[256 * 64];
  const int bid = blockIdx.x;
  int m, n, nf = 0;
  if (GATED) {
    m = bid >> 3;
    n = bid & 7;
    nf = min(*nflag, CAP1);
    if (m >= ((nf + 127) >> 7)) return;
  } else {
    const int q = bid >> 3;
    m = (q & 7) * 32 + (q >> 3);
    n = bid & 7;
  }
  const int m0 = m * 128;
  const int n0 = n * 256;
  const int t = threadIdx.x;
  const int wid = t >> 6, wr = wid >> 1, wc = wid & 1;
  const int lr = t & 15, lg = (t >> 4) & 3;
  size_t arow[4];
#pragma unroll
  for (int i = 0; i < 4; ++i) {
    const int g = m0 + i * 32 + (t >> 3);
    const int src = GATED ? flags[g < nf ? g : nf - 1] : g;
    arow[i] = (size_t)src * 1024;
  }

  f32x4 acc[4][8];
#pragma unroll
  for (int mi = 0; mi < 4; ++mi)
#pragma unroll
    for (int ni = 0; ni < 8; ++ni) acc[mi][ni] = (f32x4){0.f, 0.f, 0.f, 0.f};

  kloop64<TERMS, TERMS * 8>(A, B + (size_t)n0 * 1024, arow, Asm, Bsm, acc,
                            t, wr, wc, lr, lg);

  float en[8]; int kb[8];
#pragma unroll
  for (int ni = 0; ni < 8; ++ni) {
    kb[ni] = n0 + wc * 128 + ni * 16 + lr;
    en[ni] = enorms[kb[ni]];
  }
  const int p = n * 2 + wc;
#pragma unroll
  for (int mi = 0; mi < 4; ++mi)
#pragma unroll
    for (int j = 0; j < 4; ++j) {
      float bv = fmaf(-2.f, acc[mi][0][j], en[0]);
      int bk = kb[0];
      float sv = FLT_MAX;
#pragma unroll
      for (int ni = 1; ni < 8; ++ni) {
        const float v = fmaf(-2.f, acc[mi][ni][j], en[ni]);
        if (v < bv) { sv = bv; bv = v; bk = kb[ni]; }
        else sv = fminf(sv, v);
      }
#pragma unroll
      for (int msk = 1; msk < 16; msk <<= 1) {
        const float ob = __shfl_xor(bv, msk);
        const int   ok = __shfl_xor(bk, msk);
        const float os = __shfl_xor(sv, msk);
        if (ob < bv || (ob == bv && ok < bk)) { sv = fminf(bv, os); bv = ob; bk = ok; }
        else sv = fminf(sv, ob);
      }
      if (lr == 0) {
        const int row = m0 + wr * 64 + mi * 16 + lg * 4 + j;
        pval[(size_t)p * mrows + row] = bv;
        psec[(size_t)p * mrows + row] = sv;
        pidx[(size_t)p * mrows + row] = bk;
      }
    }
}

// merge 16 panel partials -> provisional best; flag ambiguous rows (eps1)
__global__ __launch_bounds__(256) void kreduce(const float* __restrict__ pval,
    const float* __restrict__ psec, const int* __restrict__ pidx,
    int* __restrict__ idx, int* __restrict__ nflag, int* __restrict__ flags) {
  const int r = blockIdx.x * 256 + threadIdx.x;
  float bv = FLT_MAX, sv = FLT_MAX;
  int bk = 0;
#pragma unroll
  for (int p = 0; p < 16; ++p) {
    const float v1 = pval[p * NROWS + r];
    const int   k1 = pidx[p * NROWS + r];
    const float s1 = psec[p * NROWS + r];
    if (v1 < bv || (v1 == bv && k1 < bk)) { sv = fminf(bv, s1); bv = v1; bk = k1; }
    else sv = fminf(sv, v1);
  }
  idx[r] = bk;
  if (sv - bv < EPS1) {
    const int pos = atomicAdd(nflag, 1);
    if (pos < CAP1) flags[pos] = r;
  }
}

// merge stage-2 partials: confident rows -> final idx; near-ties -> stage-3
__global__ __launch_bounds__(256) void kreduce2(const float* __restrict__ pval2,
    const float* __restrict__ psec2, const int* __restrict__ pidx2,
    const int* __restrict__ flags, const int* __restrict__ nflag,
    int* __restrict__ idx, int* __restrict__ nflag2, int* __restrict__ flags2) {
  const int nf = min(*nflag, CAP1);
  const int g = blockIdx.x * 256 + threadIdx.x;
  if (g >= nf) return;
  float bv = FLT_MAX, sv = FLT_MAX;
  int bk = 0;
#pragma unroll
  for (int p = 0; p < 16; ++p) {
    const float v1 = pval2[p * CAP1 + g];
    const int   k1 = pidx2[p * CAP1 + g];
    const float s1 = psec2[p * CAP1 + g];
    if (v1 < bv || (v1 == bv && k1 < bk)) { sv = fminf(bv, s1); bv = v1; bk = k1; }
    else sv = fminf(sv, v1);
  }
  const int r = flags[g];
  if (sv - bv >= EPS2) {
    idx[r] = bk;
  } else {
    const int pos = atomicAdd(nflag2, 1);
    if (pos < CAP2) flags2[pos] = r;
  }
}

// parallel fp32 rescore: block = (row g2 = bid>>3, chunk = bid&7);
// ONE code per thread -> latency hidden by TLP (r17-proven).
__global__ __launch_bounds__(256) void krescore_p(
    const unsigned short* __restrict__ Ap, const float* __restrict__ emb,
    const float* __restrict__ enorms, const int* __restrict__ flags2,
    const int* __restrict__ nflag2, float* __restrict__ rbest,
    int* __restrict__ rbidx) {
  const int nf2 = min(*nflag2, CAP2);
  const int g2 = blockIdx.x >> 3;
  if (g2 >= nf2) return;
  const int chunk = blockIdx.x & 7;
  const int t = threadIdx.x;
  const int r = flags2[g2];
  __shared__ float hr[512];
  __shared__ float rv[256];
  __shared__ int   rk[256];
  for (int i = t; i < 128; i += 256) {
    const ushort4 hh = *(const ushort4*)&Ap[(size_t)r * 1024 + i * 4];
    const ushort4 ll = *(const ushort4*)&Ap[(size_t)r * 1024 + 512 + i * 4];
    hr[i * 4 + 0] = bf2f(hh.x) + bf2f(ll.x);
    hr[i * 4 + 1] = bf2f(hh.y) + bf2f(ll.y);
    hr[i * 4 + 2] = bf2f(hh.z) + bf2f(ll.z);
    hr[i * 4 + 3] = bf2f(hh.w) + bf2f(ll.w);
  }
  __syncthreads();
  const int c = chunk * 256 + t;
  const float* er = emb + (size_t)c * 512;
  float d0 = 0.f, d1 = 0.f, d2 = 0.f, d3 = 0.f;
#pragma unroll 8
  for (int dd = 0; dd < 512; dd += 16) {
    const float4 e0 = *(const float4*)&er[dd];
    const float4 e1 = *(const float4*)&er[dd + 4];
    const float4 e2 = *(const float4*)&er[dd + 8];
    const float4 e3 = *(const float4*)&er[dd + 12];
    d0 = fmaf(hr[dd+0],  e0.x, d0); d0 = fmaf(hr[dd+1],  e0.y, d0);
    d0 = fmaf(hr[dd+2],  e0.z, d0); d0 = fmaf(hr[dd+3],  e0.w, d0);
    d1 = fmaf(hr[dd+4],  e1.x, d1); d1 = fmaf(hr[dd+5],  e1.y, d1);
    d1 = fmaf(hr[dd+6],  e1.z, d1); d1 = fmaf(hr[dd+7],  e1.w, d1);
    d2 = fmaf(hr[dd+8],  e2.x, d2); d2 = fmaf(hr[dd+9],  e2.y, d2);
    d2 = fmaf(hr[dd+10], e2.z, d2); d2 = fmaf(hr[dd+11], e2.w, d2);
    d3 = fmaf(hr[dd+12], e3.x, d3); d3 = fmaf(hr[dd+13], e3.y, d3);
    d3 = fmaf(hr[dd+14], e3.z, d3); d3 = fmaf(hr[dd+15], e3.w, d3);
  }
  const float dot = (d0 + d1) + (d2 + d3);
  rv[t] = fmaf(-2.f, dot, enorms[c]);
  rk[t] = c;
  __syncthreads();
  for (int off = 128; off > 0; off >>= 1) {
    if (t < off) {
      const float v2 = rv[t + off];
      const int   k2 = rk[t + off];
      if (v2 < rv[t] || (v2 == rv[t] && k2 < rk[t])) { rv[t] = v2; rk[t] = k2; }
    }
    __syncthreads();
  }
  if (t == 0) {
    rbest[g2 * 8 + chunk] = rv[0];
    rbidx[g2 * 8 + chunk] = rk[0];
  }
}

// merge 8 chunk-results per rescored row -> final idx
__global__ __launch_bounds__(256) void kpick(const float* __restrict__ rbest,
    const int* __restrict__ rbidx, const int* __restrict__ flags2,
    const int* __restrict__ nflag2, int* __restrict__ idx) {
  const int g2 = blockIdx.x * 256 + threadIdx.x;
  if (g2 >= min(*nflag2, CAP2)) return;
  float bv = rbest[g2 * 8];
  int   bk = rbidx[g2 * 8];
#pragma unroll
  for (int c = 1; c < 8; ++c) {
    const float v = rbest[g2 * 8 + c];
    const int   k = rbidx[g2 * 8 + c];
    if (v < bv || (v == bv && k < bk)) { bv = v; bk = k; }
  }
  idx[flags2[g2]] = bk;
}

// q_st + loss partial + histogram; h reconstructed from Ap (hi+lo).
__global__ __launch_bounds__(256) void kquant(const unsigned short* __restrict__ Ap,
    const float* __restrict__ emb, const int* __restrict__ idx,
    float* __restrict__ qout, double* __restrict__ partials,
    int* __restrict__ counts) {
  const int t = threadIdx.x;
  const int base = blockIdx.x * 256 + t;   // 2048 x 256 = 524,288 per pass
  float ls = 0.f;
#pragma unroll
  for (int i = 0; i < 8; ++i) {
    const int f4 = base + i * 524288;      // 4,194,304 float4 total
    const int n  = f4 >> 7;
    const int c4 = (f4 & 127) << 2;
    const int in = idx[n];
    const ushort4 hh = *(const ushort4*)&Ap[(size_t)n * 1024 + c4];
    const ushort4 ll = *(const ushort4*)&Ap[(size_t)n * 1024 + 512 + c4];
    const float hx = bf2f(hh.x) + bf2f(ll.x);
    const float hy = bf2f(hh.y) + bf2f(ll.y);
    const float hz = bf2f(hh.z) + bf2f(ll.z);
    const float hw = bf2f(hh.w) + bf2f(ll.w);
    const float4 ev = *(const float4*)&emb[(size_t)in * DDIM + c4];
    f32x4 q;
    q.x = hx + (ev.x - hx);
    q.y = hy + (ev.y - hy);
    q.z = hz + (ev.z - hz);
    q.w = hw + (ev.w - hw);
    __builtin_nontemporal_store(q, (f32x4*)&qout[(size_t)f4 * 4]);
    const float dx = ev.x - hx, dy = ev.y - hy;
    const float dz = ev.z - hz, dw = ev.w - hw;
    ls += dx * dx + dy * dy + dz * dz + dw * dw;
    if (c4 == 0) atomicAdd(&counts[in], 1);
  }
  double s = (double)ls;
#pragma unroll
  for (int off = 32; off > 0; off >>= 1) s += __shfl_down(s, off);
  __shared__ double sred[4];
  if ((t & 63) == 0) sred[t >> 6] = s;
  __syncthreads();
  if (t == 0)
    partials[blockIdx.x] = sred[0] + sred[1] + sred[2] + sred[3];
}

// encodings one-hot, float4 nontemporal streams (runs AFTER kquant)
__global__ __launch_bounds__(256) void kenc(const int* __restrict__ idx,
                                            float* __restrict__ outf) {
  const int tid = blockIdx.x * 256 + threadIdx.x;  // 16384 x 256
#pragma unroll
  for (int j = 0; j < 4; ++j) {
    const int f4 = tid + j * 4194304;   // 16,777,216 float4 total
    const int n  = f4 >> 9;             // 512 float4 per row
    const int k4 = (f4 & 511) << 2;
    const int in = idx[n];
    f32x4 v = {0.f, 0.f, 0.f, 0.f};
    if ((in & ~3) == k4) v[in & 3] = 1.f;
    __builtin_nontemporal_store(v, (f32x4*)&outf[(size_t)f4 * 4]);
  }
}

__global__ __launch_bounds__(256) void kfinal(const double* __restrict__ partials,
    const int* __restrict__ counts, float* __restrict__ out) {
  __shared__ double sred[256];
  const int t = threadIdx.x;
  double s = 0.0;
  for (int k = t; k < 2048; k += 256) s += partials[k];
  sred[t] = s;
  __syncthreads();
  for (int off = 128; off > 0; off >>= 1) {
    if (t < off) sred[t] += sred[t + off];
    __syncthreads();
  }
  const double loss_sum = sred[0];
  __syncthreads();
  double e = 0.0;
  for (int k = t; k < KCODES; k += 256) {
    const double p = counts[k] / 32768.0;
    e += p * log(p + 1e-10);
  }
  sred[t] = e;
  __syncthreads();
  for (int off = 128; off > 0; off >>= 1) {
    if (t < off) sred[t] += sred[t + off];
    __syncthreads();
  }
  if (t == 0) {
    out[0]        = (float)(0.25 * loss_sum / (32768.0 * 512.0));
    out[OUT_PERP] = (float)exp(-sred[0]);
  }
}

extern "C" void kernel_launch(void* const* d_in, const int* in_sizes, int n_in,
                              void* d_out, int out_size, void* d_ws, size_t ws_size,
                              hipStream_t stream) {
  const float* x0  = (const float*)d_in[0];
  const float* x1  = (const float*)d_in[1];
  const float* W   = (const float*)d_in[2];
  const float* b   = (const float*)d_in[3];
  const float* emb = (const float*)d_in[4];
  float* out = (float*)d_out;
  float* S   = out + OUT_ENC + 2;

  unsigned short* Ap = (unsigned short*)(S + AP_OFF);
  unsigned short* Bp = (unsigned short*)(S + BP_OFF);
  unsigned short* Xs = (unsigned short*)(S + XS_OFF);
  unsigned short* Ws = (unsigned short*)(S + WS_OFF);
  int* pidx  = (int*)(S + PIDX_OFF);
  int* pidx2 = (int*)(S + PIDX2_OFF);
  int* rbidx = (int*)(S + RI_OFF);

  int* nflag  = (int*)((char*)d_ws + 8);
  int* nflag2 = (int*)((char*)d_ws + 12);
  int* counts = (int*)((char*)d_ws + 16);
  int* idx    = (int*)((char*)d_ws + 8208);
  int* flags  = (int*)((char*)d_ws + 139280);     // CAP1 ints
  int* flags2 = (int*)((char*)d_ws + 204816);     // CAP2 ints
  double* partials = (double*)((char*)d_ws + 221200);  // 2048 doubles

  kprep<<<17665, 256, 0, stream>>>(x0, x1, W, emb, Xs, Ws, Bp,
                                   S + ENORM_OFF, (unsigned int*)d_ws);
  kgemm1_mfma<<<512, 256, 0, stream>>>(Xs, Ws, b, Ap);
  kdist_t<1, false><<<2048, 256, 0, stream>>>(Ap, Bp, S + ENORM_OFF,
      S + PVAL_OFF, S + PSEC_OFF, pidx, nflag, nullptr, NROWS);
  kreduce<<<128, 256, 0, stream>>>(S + PVAL_OFF, S + PSEC_OFF, pidx, idx, nflag, flags);
  kdist_t<3, true><<<1024, 256, 0, stream>>>(Ap, Bp, S + ENORM_OFF,
      S + PVAL2_OFF, S + PSEC2_OFF, pidx2, nflag, flags, CAP1);
  kreduce2<<<64, 256, 0, stream>>>(S + PVAL2_OFF, S + PSEC2_OFF, pidx2,
                                   flags, nflag, idx, nflag2, flags2);
  krescore_p<<<CAP2 * 8, 256, 0, stream>>>(Ap, emb, S + ENORM_OFF,
      flags2, nflag2, S + RB_OFF, rbidx);
  kpick<<<16, 256, 0, stream>>>(S + RB_OFF, rbidx, flags2, nflag2, idx);
  kquant<<<2048, 256, 0, stream>>>(Ap, emb, idx, out + OUT_Q, partials, counts);
  kenc<<<16384, 256, 0, stream>>>(idx, out + OUT_ENC);
  kfinal<<<1, 256, 0, stream>>>(partials, counts, out);
}

// Round 20
// 476.800 us; speedup vs baseline: 1.3143x; 1.3143x over previous
//
#include <hip/hip_runtime.h>
#include <cfloat>
#include <cmath>

#define NROWS 32768
#define DDIM  512
#define KCODES 2048

// output layout (floats): [loss][q_st N*512][perplexity][encodings N*K]
#define OUT_Q    1
#define OUT_PERP 16777217
#define OUT_ENC  16777218

// scratch offsets in float slots, relative to S = d_out + OUT_ENC + 2
#define AP_OFF    16777216    // 16,777,216  h split bf16 [32768][1024] (hi|lo)
#define BP_OFF    33554432    //  1,048,576  emb split bf16 [2048][1024]
#define XS_OFF    34603008    // 16,777,216  X split bf16 [32768][1024]
#define WS_OFF    51380224    //    262,144  W split bf16 [512][1024]
#define ENORM_OFF 51642368    //      2,048
#define PVAL_OFF  51644416    //  1,048,576 (32 x 32768)
#define PSEC_OFF  52692992    //  1,048,576
#define PIDX_OFF  53741568    //  1,048,576
#define PVAL2_OFF 63178752    //    524,288 (32 x 16384)
#define PSEC2_OFF 63703040    //    524,288
#define PIDX2_OFF 64227328    //    524,288
#define RB_OFF    64751616    //     32,768 (CAP2 x 8 chunk-best vals)
#define RI_OFF    64784384    //     32,768 (CAP2 x 8 chunk-best idx) -> end 64,817,152

#define CAP1 16384
#define CAP2 4096
#define EPS1 0.32f            // 1-term flag margin (r12-proven pass)
#define EPS2 0.02f            // 3-term flag margin (r3/r4-proven)

typedef __attribute__((ext_vector_type(8))) short  bf16x8;
typedef __attribute__((ext_vector_type(4))) float  f32x4;

__device__ __forceinline__ unsigned short f2bf(float f) {
  unsigned u = __float_as_uint(f);
  unsigned r = (u + 0x7FFF + ((u >> 16) & 1)) >> 16;
  return (unsigned short)r;
}
__device__ __forceinline__ float bf2f(unsigned short h) {
  return __uint_as_float(((unsigned)h) << 16);
}
__device__ __forceinline__ void gload16(const void* g, void* l) {
  __builtin_amdgcn_global_load_lds(
      (const __attribute__((address_space(1))) unsigned int*)g,
      (__attribute__((address_space(3))) unsigned int*)l, 16, 0, 0);
}
__device__ __forceinline__ ushort4 hi4(float4 v) {
  return make_ushort4(f2bf(v.x), f2bf(v.y), f2bf(v.z), f2bf(v.w));
}
__device__ __forceinline__ ushort4 lo4(float4 v, ushort4 h) {
  return make_ushort4(f2bf(v.x - bf2f(h.x)), f2bf(v.y - bf2f(h.y)),
                      f2bf(v.z - bf2f(h.z)), f2bf(v.w - bf2f(h.w)));
}

// ---- BK=64 single-buffer K-loop (r7/r18-proven local optimum) -----------
// A rows are addressed via precomputed per-thread element offsets arow[4]
// (supports flags[]-indirect gather: gload_lds global src is per-lane).
template<int TERMS, int KSTEPS>
__device__ __forceinline__ void kloop64(const unsigned short* __restrict__ Abase,
    const unsigned short* __restrict__ Bm, const size_t* __restrict__ arow,
    short* Asm, short* Bsm, f32x4 (&acc)[4][4],
    int t, int wr, int wc, int lr, int lg) {
  for (int kt = 0; kt < KSTEPS; ++kt) {
    const int ph = kt >> 3, r64 = (kt & 7) * 64;
    int koffA, koffB;
    if (TERMS == 1)      { koffA = r64;                          koffB = r64; }
    else if (TERMS == 3) { koffA = (ph == 1) ? 512 + r64 : r64;  koffB = (ph == 2) ? 512 + r64 : r64; }
    else                 { koffA = (ph & 1) ? 512 + r64 : r64;   koffB = (ph & 2) ? 512 + r64 : r64; }
    const unsigned short* Bgp = Bm + koffB;
#pragma unroll
    for (int i = 0; i < 4; ++i) {
      const int chunk = i * 256 + t;
      const int r = chunk >> 3;
      const int c8s = (chunk & 7) ^ (r & 7);
      gload16(Abase + arow[i] + koffA + c8s * 8, Asm + chunk * 8);
      gload16(Bgp + (size_t)r * 1024 + c8s * 8, Bsm + chunk * 8);
    }
    __syncthreads();
#pragma unroll
    for (int kk = 0; kk < 2; ++kk) {
      const int xk = (kk * 32 + lg * 8) ^ ((lr & 7) << 3);
      bf16x8 a[4], b[4];
#pragma unroll
      for (int mi = 0; mi < 4; ++mi)
        a[mi] = *(const bf16x8*)&Asm[(wr * 64 + mi * 16 + lr) * 64 + xk];
#pragma unroll
      for (int ni = 0; ni < 4; ++ni)
        b[ni] = *(const bf16x8*)&Bsm[(wc * 64 + ni * 16 + lr) * 64 + xk];
#pragma unroll
      for (int mi = 0; mi < 4; ++mi)
#pragma unroll
        for (int ni = 0; ni < 4; ++ni)
          acc[mi][ni] = __builtin_amdgcn_mfma_f32_16x16x32_bf16(a[mi], b[ni], acc[mi][ni], 0, 0, 0);
    }
    __syncthreads();
  }
}

// ---- fully fused preprocessing: x0|x1 split, W split, ws clear, emb split+norms
__global__ __launch_bounds__(256) void kprep(const float* __restrict__ x0,
    const float* __restrict__ x1, const float* __restrict__ W,
    const float* __restrict__ emb, unsigned short* __restrict__ Xs,
    unsigned short* __restrict__ Ws, unsigned short* __restrict__ Bp,
    float* __restrict__ enorms, unsigned int* __restrict__ wsclr) {
  const int bid = blockIdx.x;
  const int t = threadIdx.x;
  if (bid < 16384) {                     // x halves -> Xs
    const int i = bid * 256 + t;
    const int half = i >> 21;
    const int j = i & 2097151;
    const int n = j >> 6;
    const int c4 = (j & 63) * 4;
    const float* src = half ? x1 : x0;
    const float4 v = *(const float4*)&src[(size_t)n * 256 + c4];
    const ushort4 hh = hi4(v);
    unsigned short* row = Xs + (size_t)n * 1024 + half * 256;
    *(ushort4*)&row[c4]       = hh;
    *(ushort4*)&row[512 + c4] = lo4(v, hh);
  } else if (bid < 16640) {              // W -> Ws
    const int j = (bid - 16384) * 256 + t;
    const int r = j >> 7;
    const int c4 = (j & 127) * 4;
    const float4 v = *(const float4*)&W[(size_t)r * 512 + c4];
    const ushort4 hh = hi4(v);
    unsigned short* row = Ws + (size_t)r * 1024;
    *(ushort4*)&row[c4]       = hh;
    *(ushort4*)&row[512 + c4] = lo4(v, hh);
  } else if (bid == 16640) {             // ws header clear
    for (int i = t; i < 2052; i += 256) wsclr[i] = 0u;
  } else {                               // emb -> Bp + enorms (2 rows/block)
    __shared__ float part[4];
    const int row = (bid - 16641) * 2 + (t >> 7);
    const int c4 = (t & 127) * 4;
    const float4 v = *(const float4*)&emb[(size_t)row * 512 + c4];
    const ushort4 hh = hi4(v);
    unsigned short* brow = Bp + (size_t)row * 1024;
    *(ushort4*)&brow[c4]       = hh;
    *(ushort4*)&brow[512 + c4] = lo4(v, hh);
    float s = v.x * v.x + v.y * v.y + v.z * v.z + v.w * v.w;
#pragma unroll
    for (int off = 32; off > 0; off >>= 1) s += __shfl_down(s, off);
    if ((t & 63) == 0) part[t >> 6] = s;
    __syncthreads();
    if (t == 0)   enorms[row] = part[0] + part[1];
    if (t == 128) enorms[row] = part[2] + part[3];
  }
}

// ---- h = X @ W^T + b, 4-term split-bf16 MFMA; writes only Ap (hi|lo) ----
__global__ __launch_bounds__(256) void kgemm1_mfma(
    const unsigned short* __restrict__ Xs, const unsigned short* __restrict__ Ws,
    const float* __restrict__ bias, unsigned short* __restrict__ Ap) {
  __shared__ short Asm[128 * 64];
  __shared__ short Bsm[128 * 64];
  const int bid = blockIdx.x;               // 1024 blocks
  const int n = (bid >> 3) & 3;
  const int m = (bid & 7) * 32 + (bid >> 5);
  const int m0 = m * 128, j0 = n * 128;
  const int t = threadIdx.x;
  const int wid = t >> 6, wr = wid >> 1, wc = wid & 1;
  const int lr = t & 15, lg = (t >> 4) & 3;
  size_t arow[4];
#pragma unroll
  for (int i = 0; i < 4; ++i)
    arow[i] = (size_t)(m0 + i * 32 + (t >> 3)) * 1024;

  f32x4 acc[4][4];
#pragma unroll
  for (int mi = 0; mi < 4; ++mi)
#pragma unroll
    for (int ni = 0; ni < 4; ++ni) acc[mi][ni] = (f32x4){0.f, 0.f, 0.f, 0.f};

  kloop64<4, 32>(Xs, Ws + (size_t)j0 * 1024, arow, Asm, Bsm, acc, t, wr, wc, lr, lg);

#pragma unroll
  for (int ni = 0; ni < 4; ++ni) {
    const int col = j0 + wc * 64 + ni * 16 + lr;
    const float bb = bias[col];
#pragma unroll
    for (int mi = 0; mi < 4; ++mi)
#pragma unroll
      for (int jj = 0; jj < 4; ++jj) {
        const int row = m0 + wr * 64 + mi * 16 + lg * 4 + jj;
        const float v = acc[mi][ni][jj] + bb;
        const unsigned short hb = f2bf(v);
        Ap[(size_t)row * 1024 + col]       = hb;
        Ap[(size_t)row * 1024 + 512 + col] = f2bf(v - bf2f(hb));
      }
  }
}

// ---- distance GEMM (argmin partials) ------------------------------------
// GATED: m-panel rows gathered indirectly via flags[] (no Ag copy).
template<int TERMS, bool GATED>
__global__ __launch_bounds__(256) void kdist_t(
    const unsigned short* __restrict__ A, const unsigned short* __restrict__ B,
    const float* __restrict__ enorms, float* __restrict__ pval,
    float* __restrict__ psec, int* __restrict__ pidx,
    const int* __restrict__ nflag, const int* __restrict__ flags, int mrows) {
  __shared__ short Asm[128 * 64];
  __shared__ short Bsm[128 * 64];
  const int bid = blockIdx.x;
  int m, n, nf = 0;
  if (GATED) {
    m = bid >> 4;
    n = bid & 15;
    nf = min(*nflag, CAP1);
    if (m >= ((nf + 127) >> 7)) return;
  } else {
    m = (bid & 7) * 32 + (bid >> 7);
    n = (bid >> 3) & 15;
  }
  const int m0 = m * 128;
  const int n0 = n * 128;
  const int t = threadIdx.x;
  const int wid = t >> 6, wr = wid >> 1, wc = wid & 1;
  const int lr = t & 15, lg = (t >> 4) & 3;
  size_t arow[4];
#pragma unroll
  for (int i = 0; i < 4; ++i) {
    const int g = m0 + i * 32 + (t >> 3);
    const int src = GATED ? flags[g < nf ? g : nf - 1] : g;
    arow[i] = (size_t)src * 1024;
  }

  f32x4 acc[4][4];
#pragma unroll
  for (int mi = 0; mi < 4; ++mi)
#pragma unroll
    for (int ni = 0; ni < 4; ++ni) acc[mi][ni] = (f32x4){0.f, 0.f, 0.f, 0.f};

  kloop64<TERMS, TERMS * 8>(A, B + (size_t)n0 * 1024, arow, Asm, Bsm, acc,
                            t, wr, wc, lr, lg);

  float en[4]; int kb[4];
#pragma unroll
  for (int ni = 0; ni < 4; ++ni) {
    kb[ni] = n0 + wc * 64 + ni * 16 + lr;
    en[ni] = enorms[kb[ni]];
  }
  const int p = n * 2 + wc;
#pragma unroll
  for (int mi = 0; mi < 4; ++mi)
#pragma unroll
    for (int j = 0; j < 4; ++j) {
      float bv = fmaf(-2.f, acc[mi][0][j], en[0]);
      int bk = kb[0];
      float sv = FLT_MAX;
#pragma unroll
      for (int ni = 1; ni < 4; ++ni) {
        const float v = fmaf(-2.f, acc[mi][ni][j], en[ni]);
        if (v < bv) { sv = bv; bv = v; bk = kb[ni]; }
        else sv = fminf(sv, v);
      }
#pragma unroll
      for (int msk = 1; msk < 16; msk <<= 1) {
        const float ob = __shfl_xor(bv, msk);
        const int   ok = __shfl_xor(bk, msk);
        const float os = __shfl_xor(sv, msk);
        if (ob < bv || (ob == bv && ok < bk)) { sv = fminf(bv, os); bv = ob; bk = ok; }
        else sv = fminf(sv, ob);
      }
      if (lr == 0) {
        const int row = m0 + wr * 64 + mi * 16 + lg * 4 + j;
        pval[(size_t)p * mrows + row] = bv;
        psec[(size_t)p * mrows + row] = sv;
        pidx[(size_t)p * mrows + row] = bk;
      }
    }
}

// merge 32 panel partials -> provisional best; flag ambiguous rows (eps1)
__global__ __launch_bounds__(256) void kreduce(const float* __restrict__ pval,
    const float* __restrict__ psec, const int* __restrict__ pidx,
    int* __restrict__ idx, int* __restrict__ nflag, int* __restrict__ flags) {
  const int r = blockIdx.x * 256 + threadIdx.x;
  float bv = FLT_MAX, sv = FLT_MAX;
  int bk = 0;
#pragma unroll
  for (int p = 0; p < 32; ++p) {
    const float v1 = pval[p * NROWS + r];
    const int   k1 = pidx[p * NROWS + r];
    const float s1 = psec[p * NROWS + r];
    if (v1 < bv || (v1 == bv && k1 < bk)) { sv = fminf(bv, s1); bv = v1; bk = k1; }
    else sv = fminf(sv, v1);
  }
  idx[r] = bk;
  if (sv - bv < EPS1) {
    const int pos = atomicAdd(nflag, 1);
    if (pos < CAP1) flags[pos] = r;
  }
}

// merge stage-2 partials: confident rows -> final idx; near-ties -> stage-3
__global__ __launch_bounds__(256) void kreduce2(const float* __restrict__ pval2,
    const float* __restrict__ psec2, const int* __restrict__ pidx2,
    const int* __restrict__ flags, const int* __restrict__ nflag,
    int* __restrict__ idx, int* __restrict__ nflag2, int* __restrict__ flags2) {
  const int nf = min(*nflag, CAP1);
  const int g = blockIdx.x * 256 + threadIdx.x;
  if (g >= nf) return;
  float bv = FLT_MAX, sv = FLT_MAX;
  int bk = 0;
#pragma unroll
  for (int p = 0; p < 32; ++p) {
    const float v1 = pval2[p * CAP1 + g];
    const int   k1 = pidx2[p * CAP1 + g];
    const float s1 = psec2[p * CAP1 + g];
    if (v1 < bv || (v1 == bv && k1 < bk)) { sv = fminf(bv, s1); bv = v1; bk = k1; }
    else sv = fminf(sv, v1);
  }
  const int r = flags[g];
  if (sv - bv >= EPS2) {
    idx[r] = bk;
  } else {
    const int pos = atomicAdd(nflag2, 1);
    if (pos < CAP2) flags2[pos] = r;
  }
}

// parallel fp32 rescore: block = (row g2 = bid>>3, chunk = bid&7);
// ONE code per thread -> latency hidden by TLP (r17-proven).
__global__ __launch_bounds__(256) void krescore_p(
    const unsigned short* __restrict__ Ap, const float* __restrict__ emb,
    const float* __restrict__ enorms, const int* __restrict__ flags2,
    const int* __restrict__ nflag2, float* __restrict__ rbest,
    int* __restrict__ rbidx) {
  const int nf2 = min(*nflag2, CAP2);
  const int g2 = blockIdx.x >> 3;
  if (g2 >= nf2) return;
  const int chunk = blockIdx.x & 7;
  const int t = threadIdx.x;
  const int r = flags2[g2];
  __shared__ float hr[512];
  __shared__ float rv[256];
  __shared__ int   rk[256];
  for (int i = t; i < 128; i += 256) {
    const ushort4 hh = *(const ushort4*)&Ap[(size_t)r * 1024 + i * 4];
    const ushort4 ll = *(const ushort4*)&Ap[(size_t)r * 1024 + 512 + i * 4];
    hr[i * 4 + 0] = bf2f(hh.x) + bf2f(ll.x);
    hr[i * 4 + 1] = bf2f(hh.y) + bf2f(ll.y);
    hr[i * 4 + 2] = bf2f(hh.z) + bf2f(ll.z);
    hr[i * 4 + 3] = bf2f(hh.w) + bf2f(ll.w);
  }
  __syncthreads();
  const int c = chunk * 256 + t;
  const float* er = emb + (size_t)c * 512;
  float d0 = 0.f, d1 = 0.f, d2 = 0.f, d3 = 0.f;
#pragma unroll 8
  for (int dd = 0; dd < 512; dd += 16) {
    const float4 e0 = *(const float4*)&er[dd];
    const float4 e1 = *(const float4*)&er[dd + 4];
    const float4 e2 = *(const float4*)&er[dd + 8];
    const float4 e3 = *(const float4*)&er[dd + 12];
    d0 = fmaf(hr[dd+0],  e0.x, d0); d0 = fmaf(hr[dd+1],  e0.y, d0);
    d0 = fmaf(hr[dd+2],  e0.z, d0); d0 = fmaf(hr[dd+3],  e0.w, d0);
    d1 = fmaf(hr[dd+4],  e1.x, d1); d1 = fmaf(hr[dd+5],  e1.y, d1);
    d1 = fmaf(hr[dd+6],  e1.z, d1); d1 = fmaf(hr[dd+7],  e1.w, d1);
    d2 = fmaf(hr[dd+8],  e2.x, d2); d2 = fmaf(hr[dd+9],  e2.y, d2);
    d2 = fmaf(hr[dd+10], e2.z, d2); d2 = fmaf(hr[dd+11], e2.w, d2);
    d3 = fmaf(hr[dd+12], e3.x, d3); d3 = fmaf(hr[dd+13], e3.y, d3);
    d3 = fmaf(hr[dd+14], e3.z, d3); d3 = fmaf(hr[dd+15], e3.w, d3);
  }
  const float dot = (d0 + d1) + (d2 + d3);
  rv[t] = fmaf(-2.f, dot, enorms[c]);
  rk[t] = c;
  __syncthreads();
  for (int off = 128; off > 0; off >>= 1) {
    if (t < off) {
      const float v2 = rv[t + off];
      const int   k2 = rk[t + off];
      if (v2 < rv[t] || (v2 == rv[t] && k2 < rk[t])) { rv[t] = v2; rk[t] = k2; }
    }
    __syncthreads();
  }
  if (t == 0) {
    rbest[g2 * 8 + chunk] = rv[0];
    rbidx[g2 * 8 + chunk] = rk[0];
  }
}

// merge 8 chunk-results per rescored row -> final idx
__global__ __launch_bounds__(256) void kpick(const float* __restrict__ rbest,
    const int* __restrict__ rbidx, const int* __restrict__ flags2,
    const int* __restrict__ nflag2, int* __restrict__ idx) {
  const int g2 = blockIdx.x * 256 + threadIdx.x;
  if (g2 >= min(*nflag2, CAP2)) return;
  float bv = rbest[g2 * 8];
  int   bk = rbidx[g2 * 8];
#pragma unroll
  for (int c = 1; c < 8; ++c) {
    const float v = rbest[g2 * 8 + c];
    const int   k = rbidx[g2 * 8 + c];
    if (v < bv || (v == bv && k < bk)) { bv = v; bk = k; }
  }
  idx[flags2[g2]] = bk;
}

// q_st + loss partial + histogram; h reconstructed from Ap (hi+lo).
__global__ __launch_bounds__(256) void kquant(const unsigned short* __restrict__ Ap,
    const float* __restrict__ emb, const int* __restrict__ idx,
    float* __restrict__ qout, double* __restrict__ partials,
    int* __restrict__ counts) {
  const int t = threadIdx.x;
  const int base = blockIdx.x * 256 + t;   // 2048 x 256 = 524,288 per pass
  float ls = 0.f;
#pragma unroll
  for (int i = 0; i < 8; ++i) {
    const int f4 = base + i * 524288;      // 4,194,304 float4 total
    const int n  = f4 >> 7;
    const int c4 = (f4 & 127) << 2;
    const int in = idx[n];
    const ushort4 hh = *(const ushort4*)&Ap[(size_t)n * 1024 + c4];
    const ushort4 ll = *(const ushort4*)&Ap[(size_t)n * 1024 + 512 + c4];
    const float hx = bf2f(hh.x) + bf2f(ll.x);
    const float hy = bf2f(hh.y) + bf2f(ll.y);
    const float hz = bf2f(hh.z) + bf2f(ll.z);
    const float hw = bf2f(hh.w) + bf2f(ll.w);
    const float4 ev = *(const float4*)&emb[(size_t)in * DDIM + c4];
    f32x4 q;
    q.x = hx + (ev.x - hx);
    q.y = hy + (ev.y - hy);
    q.z = hz + (ev.z - hz);
    q.w = hw + (ev.w - hw);
    __builtin_nontemporal_store(q, (f32x4*)&qout[(size_t)f4 * 4]);
    const float dx = ev.x - hx, dy = ev.y - hy;
    const float dz = ev.z - hz, dw = ev.w - hw;
    ls += dx * dx + dy * dy + dz * dz + dw * dw;
    if (c4 == 0) atomicAdd(&counts[in], 1);
  }
  double s = (double)ls;
#pragma unroll
  for (int off = 32; off > 0; off >>= 1) s += __shfl_down(s, off);
  __shared__ double sred[4];
  if ((t & 63) == 0) sred[t >> 6] = s;
  __syncthreads();
  if (t == 0)
    partials[blockIdx.x] = sred[0] + sred[1] + sred[2] + sred[3];
}

// encodings one-hot, float4 nontemporal streams (runs AFTER kquant)
__global__ __launch_bounds__(256) void kenc(const int* __restrict__ idx,
                                            float* __restrict__ outf) {
  const int tid = blockIdx.x * 256 + threadIdx.x;  // 16384 x 256
#pragma unroll
  for (int j = 0; j < 4; ++j) {
    const int f4 = tid + j * 4194304;   // 16,777,216 float4 total
    const int n  = f4 >> 9;             // 512 float4 per row
    const int k4 = (f4 & 511) << 2;
    const int in = idx[n];
    f32x4 v = {0.f, 0.f, 0.f, 0.f};
    if ((in & ~3) == k4) v[in & 3] = 1.f;
    __builtin_nontemporal_store(v, (f32x4*)&outf[(size_t)f4 * 4]);
  }
}

__global__ __launch_bounds__(256) void kfinal(const double* __restrict__ partials,
    const int* __restrict__ counts, float* __restrict__ out) {
  __shared__ double sred[256];
  const int t = threadIdx.x;
  double s = 0.0;
  for (int k = t; k < 2048; k += 256) s += partials[k];
  sred[t] = s;
  __syncthreads();
  for (int off = 128; off > 0; off >>= 1) {
    if (t < off) sred[t] += sred[t + off];
    __syncthreads();
  }
  const double loss_sum = sred[0];
  __syncthreads();
  double e = 0.0;
  for (int k = t; k < KCODES; k += 256) {
    const double p = counts[k] / 32768.0;
    e += p * log(p + 1e-10);
  }
  sred[t] = e;
  __syncthreads();
  for (int off = 128; off > 0; off >>= 1) {
    if (t < off) sred[t] += sred[t + off];
    __syncthreads();
  }
  if (t == 0) {
    out[0]        = (float)(0.25 * loss_sum / (32768.0 * 512.0));
    out[OUT_PERP] = (float)exp(-sred[0]);
  }
}

extern "C" void kernel_launch(void* const* d_in, const int* in_sizes, int n_in,
                              void* d_out, int out_size, void* d_ws, size_t ws_size,
                              hipStream_t stream) {
  const float* x0  = (const float*)d_in[0];
  const float* x1  = (const float*)d_in[1];
  const float* W   = (const float*)d_in[2];
  const float* b   = (const float*)d_in[3];
  const float* emb = (const float*)d_in[4];
  float* out = (float*)d_out;
  float* S   = out + OUT_ENC + 2;

  unsigned short* Ap = (unsigned short*)(S + AP_OFF);
  unsigned short* Bp = (unsigned short*)(S + BP_OFF);
  unsigned short* Xs = (unsigned short*)(S + XS_OFF);
  unsigned short* Ws = (unsigned short*)(S + WS_OFF);
  int* pidx  = (int*)(S + PIDX_OFF);
  int* pidx2 = (int*)(S + PIDX2_OFF);
  int* rbidx = (int*)(S + RI_OFF);

  int* nflag  = (int*)((char*)d_ws + 8);
  int* nflag2 = (int*)((char*)d_ws + 12);
  int* counts = (int*)((char*)d_ws + 16);
  int* idx    = (int*)((char*)d_ws + 8208);
  int* flags  = (int*)((char*)d_ws + 139280);     // CAP1 ints
  int* flags2 = (int*)((char*)d_ws + 204816);     // CAP2 ints
  double* partials = (double*)((char*)d_ws + 221200);  // 2048 doubles

  kprep<<<17665, 256, 0, stream>>>(x0, x1, W, emb, Xs, Ws, Bp,
                                   S + ENORM_OFF, (unsigned int*)d_ws);
  kgemm1_mfma<<<1024, 256, 0, stream>>>(Xs, Ws, b, Ap);
  kdist_t<1, false><<<4096, 256, 0, stream>>>(Ap, Bp, S + ENORM_OFF,
      S + PVAL_OFF, S + PSEC_OFF, pidx, nflag, nullptr, NROWS);
  kreduce<<<128, 256, 0, stream>>>(S + PVAL_OFF, S + PSEC_OFF, pidx, idx, nflag, flags);
  kdist_t<3, true><<<2048, 256, 0, stream>>>(Ap, Bp, S + ENORM_OFF,
      S + PVAL2_OFF, S + PSEC2_OFF, pidx2, nflag, flags, CAP1);
  kreduce2<<<64, 256, 0, stream>>>(S + PVAL2_OFF, S + PSEC2_OFF, pidx2,
                                   flags, nflag, idx, nflag2, flags2);
  krescore_p<<<CAP2 * 8, 256, 0, stream>>>(Ap, emb, S + ENORM_OFF,
      flags2, nflag2, S + RB_OFF, rbidx);
  kpick<<<16, 256, 0, stream>>>(S + RB_OFF, rbidx, flags2, nflag2, idx);
  kquant<<<2048, 256, 0, stream>>>(Ap, emb, idx, out + OUT_Q, partials, counts);
  kenc<<<16384, 256, 0, stream>>>(idx, out + OUT_ENC);
  kfinal<<<1, 256, 0, stream>>>(partials, counts, out);
}